// Round 13
// baseline (415.499 us; speedup 1.0000x reference)
//
#include <hip/hip_runtime.h>
#include <hip/hip_bf16.h>
#include <hip/hip_fp16.h>

#define LRELU_SLOPE 0.2f

__device__ __forceinline__ float lrelu(float x) { return x > 0.f ? x : LRELU_SLOPE * x; }

typedef __attribute__((ext_vector_type(8))) short short8;
typedef __attribute__((ext_vector_type(4))) float f32x4;

__device__ __forceinline__ unsigned short f2bf(float f) {
    unsigned u = __builtin_bit_cast(unsigned, f);
    u = (u + 0x7FFFu + ((u >> 16) & 1u)) >> 16;  // RNE
    return (unsigned short)u;
}
__device__ __forceinline__ float bf2f(unsigned short b) {
    unsigned u = ((unsigned)b) << 16;
    return __builtin_bit_cast(float, u);
}

// ---------------- W pack helper (device) ----------------
template <int K>
__device__ __forceinline__ void packW_one(const float* __restrict__ W,
                                          unsigned short* __restrict__ Bhi,
                                          unsigned short* __restrict__ Blo, int g) {
    constexpr int NKC = K / 32;
    int lane = g & 63;
    int kc = (g >> 6) % NKC;
    int ct = g / (64 * NKC);
    int qd = lane >> 4, col = lane & 15;
    #pragma unroll
    for (int j = 0; j < 8; j++) {
        int k = kc * 32 + qd * 8 + j;
        float w = W[(size_t)k * 64 + ct * 16 + col];
        unsigned short h = f2bf(w);
        float rem = w - bf2f(h);
        Bhi[(size_t)g * 8 + j] = h;
        Blo[(size_t)g * 8 + j] = f2bf(rem);
    }
}

// ---------------- fused prep: zero deg/cur + pack W1 + pack W2 ----------------
__global__ __launch_bounds__(256) void k_prep(int* __restrict__ degcur, int nzero,
                                              const float* __restrict__ W1,
                                              unsigned short* __restrict__ B1h, unsigned short* __restrict__ B1l,
                                              const float* __restrict__ W2,
                                              unsigned short* __restrict__ B2h, unsigned short* __restrict__ B2l) {
    int i = blockIdx.x * 256 + threadIdx.x;
    if (i < nzero) {
        degcur[i] = 0;
    } else if (i < nzero + 2048) {
        packW_one<256>(W1, B1h, B1l, i - nzero);
    } else if (i < nzero + 2048 + 512) {
        packW_one<64>(W2, B2h, B2l, i - nzero - 2048);
    }
}

__global__ void k_hist(const int* __restrict__ dst, int* __restrict__ deg, int E) {
    int i = blockIdx.x * blockDim.x + threadIdx.x;
    if (i < E) atomicAdd(&deg[dst[i]], 1);
}

__global__ __launch_bounds__(1024) void k_scan1(const int* __restrict__ deg, int* __restrict__ off,
                                                int* __restrict__ bsums, int N) {
    int t = threadIdx.x, b = blockIdx.x;
    int idx = b * 1024 + t;
    int v = (idx < N) ? deg[idx] : 0;
    int lane = t & 63, wid = t >> 6;
    int incl = v;
    #pragma unroll
    for (int d = 1; d < 64; d <<= 1) {
        int u = __shfl_up(incl, d);
        if (lane >= d) incl += u;
    }
    __shared__ int ws[16];
    if (lane == 63) ws[wid] = incl;
    __syncthreads();
    if (wid == 0) {
        int wv = (lane < 16) ? ws[lane] : 0;
        #pragma unroll
        for (int d = 1; d < 16; d <<= 1) {
            int u = __shfl_up(wv, d);
            if (lane >= d) wv += u;
        }
        if (lane < 16) ws[lane] = wv;
    }
    __syncthreads();
    int woff = (wid > 0) ? ws[wid - 1] : 0;
    if (idx < N) off[idx] = woff + incl - v;
    if (t == 0) bsums[b] = ws[15];
}

__global__ __launch_bounds__(1024) void k_scan2(int* __restrict__ bs, int nb) {
    __shared__ int s[1024];
    int t = threadIdx.x;
    s[t] = (t < nb) ? bs[t] : 0;
    __syncthreads();
    for (int d = 1; d < 1024; d <<= 1) {
        int v = (t >= d) ? s[t - d] : 0;
        __syncthreads();
        s[t] += v;
        __syncthreads();
    }
    if (t < nb) bs[t] = t ? s[t - 1] : 0;
}

// scatter folds in the block-sum add (k_scan3 deleted; consumers use off+bs)
__global__ void k_scatter(const int* __restrict__ src, const int* __restrict__ dst,
                          const int* __restrict__ off, const int* __restrict__ bs,
                          int* __restrict__ cur, int* __restrict__ csr, int E) {
    int i = blockIdx.x * blockDim.x + threadIdx.x;
    if (i < E) {
        int d = dst[i];
        int pos = off[d] + bs[d >> 10] + atomicAdd(&cur[d], 1);
        csr[pos] = src[i];
    }
}

// ---------------- MFMA GEMM: XW(fp16) = X[N,K] @ W[K,64] + fused logits ----------------
// Split-precision bf16 (r10): 3 MFMAs (AhBh+AlBh+AhBl) => ~16-bit mantissa.
// r12: XW stored fp16 (gather footprint). Logits from fp32 acc pre-rounding.
// REGISTER-PRESSURE HISTORY: r3 clamp spill / r4 straight-line clustering spill /
// r5 sched_barrier useless / r6 dynamic loop = only reliable scope bound.
template <int K>
__global__ __launch_bounds__(256) void k_mfma(const float* __restrict__ X,
                                              const unsigned short* __restrict__ Bhi,
                                              const unsigned short* __restrict__ Blo,
                                              const float* __restrict__ a_s, const float* __restrict__ a_d,
                                              __half* __restrict__ XW, float* __restrict__ Ssrc,
                                              float* __restrict__ Sdst, int N) {
    constexpr int NKC = K / 32;
    int t = threadIdx.x, lane = t & 63, wid = t >> 6;
    int mtile = blockIdx.x * 4 + wid;
    if (mtile * 16 >= N) return;
    int m0 = mtile * 16;
    int qd = lane >> 4, col = lane & 15;

    int rA = m0 + col;
    rA = rA < N ? rA : N - 1;
    const float* xrow = X + (size_t)rA * K + qd * 8;

    const short8* bh = (const short8*)Bhi;
    const short8* bl = (const short8*)Blo;

    f32x4 acc[4];
    #pragma unroll
    for (int ct = 0; ct < 4; ct++) acc[ct] = (f32x4){0.f, 0.f, 0.f, 0.f};

    #pragma clang loop unroll(disable)
    for (int kc = 0; kc < NKC; kc++) {
        const float* xp = xrow + kc * 32;
        float4 xa = *(const float4*)xp;
        float4 xb = *(const float4*)(xp + 4);
        float xv[8] = {xa.x, xa.y, xa.z, xa.w, xb.x, xb.y, xb.z, xb.w};
        short8 ah, al;
        #pragma unroll
        for (int j = 0; j < 8; j++) {
            unsigned short h = f2bf(xv[j]);
            ah[j] = (short)h;
            al[j] = (short)f2bf(xv[j] - bf2f(h));
        }
        #pragma unroll
        for (int ct = 0; ct < 4; ct++) {
            short8 wh = bh[(ct * NKC + kc) * 64 + lane];
            short8 wl = bl[(ct * NKC + kc) * 64 + lane];
            acc[ct] = __builtin_amdgcn_mfma_f32_16x16x32_bf16(ah, wh, acc[ct], 0, 0, 0);
            acc[ct] = __builtin_amdgcn_mfma_f32_16x16x32_bf16(al, wh, acc[ct], 0, 0, 0);
            acc[ct] = __builtin_amdgcn_mfma_f32_16x16x32_bf16(ah, wl, acc[ct], 0, 0, 0);
        }
    }

    float asx[4], adx[4];
    #pragma unroll
    for (int ct = 0; ct < 4; ct++) {
        asx[ct] = a_s[ct * 16 + col];
        adx[ct] = a_d[ct * 16 + col];
    }
    #pragma unroll
    for (int r = 0; r < 4; r++) {
        int row = m0 + qd * 4 + r;
        if (row < N) {
            float vs = 0.f, vd = 0.f;
            #pragma unroll
            for (int ct = 0; ct < 4; ct++) {
                float v = acc[ct][r];
                XW[(size_t)row * 64 + ct * 16 + col] = __float2half(v);
                vs += v * asx[ct];
                vd += v * adx[ct];
            }
            #pragma unroll
            for (int d = 1; d < 16; d <<= 1) {
                vs += __shfl_xor(vs, d);
                vd += __shfl_xor(vd, d);
            }
            if (col == 0) { Ssrc[row] = vs; Sdst[row] = vd; }
        }
    }
}

// ---------------- attention + aggregate: one wave per dst node ----------------
// r13: 8-edge groups — lane=(g=lane>>3, c=lane&7); one 16B fp16 VMEM instr
// covers 8 edges (deg~11 -> 2 gather instrs/node, was 3). Per-lane weight
// precompute (r11) kept; reduce across groups = xor 8/16/32.
__global__ __launch_bounds__(256) void k_attn(const __half* __restrict__ XW, const float* __restrict__ Ssrc,
                                              const float* __restrict__ Sdst, const int* __restrict__ csr,
                                              const int* __restrict__ off, const int* __restrict__ bsums,
                                              const int* __restrict__ deg,
                                              const float* __restrict__ bias, float* __restrict__ H,
                                              int N, int do_relu) {
    int t = threadIdx.x, lane = t & 63, wid = t >> 6;
    int n = blockIdx.x * 4 + wid;
    if (n >= N) return;
    int g = lane >> 3, c = lane & 7;
    float sd = Sdst[n];
    int st = off[n] + bsums[n >> 10];
    int d = deg[n];

    // phase 1: gather logits for first 64 edges; wave max
    float eself = lrelu(Ssrc[n] + sd);
    float m = eself;
    int myS = 0;
    float myE = -1e30f;
    if (lane < d) {
        myS = csr[st + lane];
        myE = lrelu(Ssrc[myS] + sd);
        m = fmaxf(m, myE);
    }
    for (int i = 64 + lane; i < d; i += 64) {
        m = fmaxf(m, lrelu(Ssrc[csr[st + i]] + sd));
    }
    #pragma unroll
    for (int dd = 32; dd > 0; dd >>= 1) m = fmaxf(m, __shfl_xor(m, dd));

    float myW = (lane < d) ? __expf(myE - m) : 0.f;
    float wself = __expf(eself - m);
    float denom = myW;
    #pragma unroll
    for (int dd = 32; dd > 0; dd >>= 1) denom += __shfl_xor(denom, dd);
    denom += wself;  // wave-uniform

    float a8[8];
    #pragma unroll
    for (int j = 0; j < 8; j++) a8[j] = 0.f;

    auto gat = [&](int row, float w) {
        float4 raw = *(const float4*)(XW + (size_t)row * 64 + c * 8);
        const __half2* hp = (const __half2*)&raw;
        #pragma unroll
        for (int j = 0; j < 4; j++) {
            float2 f = __half22float2(hp[j]);
            a8[2 * j] += w * f.x;
            a8[2 * j + 1] += w * f.y;
        }
    };

    gat(n, (g == 0) ? wself : 0.f);
    int dcap = d < 64 ? d : 64;
    for (int i = 0; i < dcap; i += 8) {
        int idx = i + g;                       // max 63 (i<=56, g<=7)
        int si = __shfl(myS, idx);
        float wi = __shfl(myW, idx);
        if (idx >= dcap) wi = 0.f;
        gat(si, wi);
    }
    for (int i = 64; i < d; i++) {             // rare tail
        int s = csr[st + i];
        float e = lrelu(Ssrc[s] + sd);
        float w = __expf(e - m);
        denom += w;
        gat(s, (g == 0) ? w : 0.f);
    }

    // reduce across the 8 edge groups (lane xor 8,16,32)
    #pragma unroll
    for (int mask = 8; mask <= 32; mask <<= 1) {
        #pragma unroll
        for (int j = 0; j < 8; j++) a8[j] += __shfl_xor(a8[j], mask);
    }

    if (g == 0) {
        float inv = 1.f / denom;
        float o[8];
        #pragma unroll
        for (int j = 0; j < 8; j++) {
            o[j] = a8[j] * inv + bias[c * 8 + j];
            if (do_relu) o[j] = fmaxf(o[j], 0.f);
        }
        float4* hp = (float4*)&H[(size_t)n * 64 + c * 8];
        hp[0] = make_float4(o[0], o[1], o[2], o[3]);
        hp[1] = make_float4(o[4], o[5], o[6], o[7]);
    }
}

// ---------------- head ----------------
__global__ __launch_bounds__(256) void k_head(const float* __restrict__ H, const int* __restrict__ ui,
                                              const int* __restrict__ mi, const float* __restrict__ fcW,
                                              const float* __restrict__ fcb, float* __restrict__ out, int B) {
    int t = threadIdx.x, lane = t & 63, wid = t >> 6;
    int i = blockIdx.x * 4 + wid;
    if (i >= B) return;
    int u = ui[i], m = mi[i];
    float v = H[(size_t)u * 64 + lane] * fcW[lane] + H[(size_t)m * 64 + lane] * fcW[64 + lane];
    #pragma unroll
    for (int dd = 32; dd > 0; dd >>= 1) v += __shfl_xor(v, dd);
    if (lane == 0) out[i] = v + fcb[0];
}

extern "C" void kernel_launch(void* const* d_in, const int* in_sizes, int n_in,
                              void* d_out, int out_size, void* d_ws, size_t ws_size,
                              hipStream_t stream) {
    const float* x   = (const float*)d_in[0];
    const int*   ei  = (const int*)d_in[1];
    const int*   ui  = (const int*)d_in[2];
    const int*   mi  = (const int*)d_in[3];
    const float* W1  = (const float*)d_in[4];
    const float* as1 = (const float*)d_in[5];
    const float* ad1 = (const float*)d_in[6];
    const float* b1  = (const float*)d_in[7];
    const float* W2  = (const float*)d_in[8];
    const float* as2 = (const float*)d_in[9];
    const float* ad2 = (const float*)d_in[10];
    const float* b2  = (const float*)d_in[11];
    const float* fcW = (const float*)d_in[12];
    const float* fcb = (const float*)d_in[13];
    float* out = (float*)d_out;

    const int Hdim = in_sizes[5];            // 64
    const int FIN  = in_sizes[4] / Hdim;     // 256
    const int N    = in_sizes[0] / FIN;      // 100000
    const int E    = in_sizes[1] / 2;        // 1000000
    const int B    = in_sizes[2];            // 16384

    char* w = (char*)d_ws;
    auto alloc = [&](size_t bytes) -> void* {
        void* p = (void*)w;
        w += (bytes + 255) & ~(size_t)255;
        return p;
    };
    __half* xw  = (__half*)alloc((size_t)N * 64 * 2);
    float* hbuf = (float*)alloc((size_t)N * 64 * 4);
    float* ssrc = (float*)alloc((size_t)N * 4);
    float* sdst = (float*)alloc((size_t)N * 4);
    int* degcur = (int*)alloc((size_t)2 * N * 4);
    int* deg = degcur;
    int* cur = degcur + N;
    int* offv  = (int*)alloc((size_t)N * 4);
    int* bsums = (int*)alloc((size_t)1024 * 4);
    int* csr   = (int*)alloc((size_t)E * 4);
    unsigned short* b1hi = (unsigned short*)alloc((size_t)2048 * 8 * 2);
    unsigned short* b1lo = (unsigned short*)alloc((size_t)2048 * 8 * 2);
    unsigned short* b2hi = (unsigned short*)alloc((size_t)512 * 8 * 2);
    unsigned short* b2lo = (unsigned short*)alloc((size_t)512 * 8 * 2);

    const int* esrc = ei;
    const int* edst = ei + E;

    // --- fused prep: zero counters + pack both W ---
    int prepWork = 2 * N + 2048 + 512;
    k_prep<<<(prepWork + 255) / 256, 256, 0, stream>>>(degcur, 2 * N, W1, b1hi, b1lo, W2, b2hi, b2lo);

    // --- build CSR by dst (shared by both layers) ---
    k_hist<<<(E + 255) / 256, 256, 0, stream>>>(edst, deg, E);
    int nb = (N + 1023) / 1024;
    k_scan1<<<nb, 1024, 0, stream>>>(deg, offv, bsums, N);
    k_scan2<<<1, 1024, 0, stream>>>(bsums, nb);
    k_scatter<<<(E + 255) / 256, 256, 0, stream>>>(esrc, edst, offv, bsums, cur, csr, E);

    const int mfmaBlocks = ((N + 15) / 16 + 3) / 4;

    // --- layer 1 ---
    k_mfma<256><<<mfmaBlocks, 256, 0, stream>>>(x, b1hi, b1lo, as1, ad1, xw, ssrc, sdst, N);
    k_attn<<<(N + 3) / 4, 256, 0, stream>>>(xw, ssrc, sdst, csr, offv, bsums, deg, b1, hbuf, N, 1);

    // --- layer 2 ---
    k_mfma<64><<<mfmaBlocks, 256, 0, stream>>>(hbuf, b2hi, b2lo, as2, ad2, xw, ssrc, sdst, N);
    k_attn<<<(N + 3) / 4, 256, 0, stream>>>(xw, ssrc, sdst, csr, offv, bsums, deg, b2, hbuf, N, 0);

    // --- head ---
    k_head<<<(B + 3) / 4, 256, 0, stream>>>(hbuf, ui, mi, fcW, fcb, out, B);
}

// Round 14
// 414.302 us; speedup vs baseline: 1.0029x; 1.0029x over previous
//
#include <hip/hip_runtime.h>
#include <hip/hip_bf16.h>
#include <hip/hip_fp16.h>

#define LRELU_SLOPE 0.2f

__device__ __forceinline__ float lrelu(float x) { return x > 0.f ? x : LRELU_SLOPE * x; }

typedef __attribute__((ext_vector_type(8))) short short8;
typedef __attribute__((ext_vector_type(4))) float f32x4;

__device__ __forceinline__ unsigned short f2bf(float f) {
    unsigned u = __builtin_bit_cast(unsigned, f);
    u = (u + 0x7FFFu + ((u >> 16) & 1u)) >> 16;  // RNE
    return (unsigned short)u;
}
__device__ __forceinline__ float bf2f(unsigned short b) {
    unsigned u = ((unsigned)b) << 16;
    return __builtin_bit_cast(float, u);
}

// ---------------- W pack helper (device) ----------------
template <int K>
__device__ __forceinline__ void packW_one(const float* __restrict__ W,
                                          unsigned short* __restrict__ Bhi,
                                          unsigned short* __restrict__ Blo, int g) {
    constexpr int NKC = K / 32;
    int lane = g & 63;
    int kc = (g >> 6) % NKC;
    int ct = g / (64 * NKC);
    int qd = lane >> 4, col = lane & 15;
    #pragma unroll
    for (int j = 0; j < 8; j++) {
        int k = kc * 32 + qd * 8 + j;
        float w = W[(size_t)k * 64 + ct * 16 + col];
        unsigned short h = f2bf(w);
        float rem = w - bf2f(h);
        Bhi[(size_t)g * 8 + j] = h;
        Blo[(size_t)g * 8 + j] = f2bf(rem);
    }
}

// ---------------- fused prep: zero deg/cur + pack W1 + pack W2 ----------------
__global__ __launch_bounds__(256) void k_prep(int* __restrict__ degcur, int nzero,
                                              const float* __restrict__ W1,
                                              unsigned short* __restrict__ B1h, unsigned short* __restrict__ B1l,
                                              const float* __restrict__ W2,
                                              unsigned short* __restrict__ B2h, unsigned short* __restrict__ B2l) {
    int i = blockIdx.x * 256 + threadIdx.x;
    if (i < nzero) {
        degcur[i] = 0;
    } else if (i < nzero + 2048) {
        packW_one<256>(W1, B1h, B1l, i - nzero);
    } else if (i < nzero + 2048 + 512) {
        packW_one<64>(W2, B2h, B2l, i - nzero - 2048);
    }
}

__global__ __launch_bounds__(1024) void k_scan1(const int* __restrict__ deg, int* __restrict__ off,
                                                int* __restrict__ bsums, int N) {
    int t = threadIdx.x, b = blockIdx.x;
    int idx = b * 1024 + t;
    int v = (idx < N) ? deg[idx] : 0;
    int lane = t & 63, wid = t >> 6;
    int incl = v;
    #pragma unroll
    for (int d = 1; d < 64; d <<= 1) {
        int u = __shfl_up(incl, d);
        if (lane >= d) incl += u;
    }
    __shared__ int ws[16];
    if (lane == 63) ws[wid] = incl;
    __syncthreads();
    if (wid == 0) {
        int wv = (lane < 16) ? ws[lane] : 0;
        #pragma unroll
        for (int d = 1; d < 16; d <<= 1) {
            int u = __shfl_up(wv, d);
            if (lane >= d) wv += u;
        }
        if (lane < 16) ws[lane] = wv;
    }
    __syncthreads();
    int woff = (wid > 0) ? ws[wid - 1] : 0;
    if (idx < N) off[idx] = woff + incl - v;
    if (t == 0) bsums[b] = ws[15];
}

__global__ __launch_bounds__(1024) void k_scan2(int* __restrict__ bs, int nb) {
    __shared__ int s[1024];
    int t = threadIdx.x;
    s[t] = (t < nb) ? bs[t] : 0;
    __syncthreads();
    for (int d = 1; d < 1024; d <<= 1) {
        int v = (t >= d) ? s[t - d] : 0;
        __syncthreads();
        s[t] += v;
        __syncthreads();
    }
    if (t < nb) bs[t] = t ? s[t - 1] : 0;
}

// ---------------- MFMA GEMM body (device): XW(fp16) = X[N,K]@W[K,64] + logits ----
// Split-precision bf16 (r10): 3 MFMAs (AhBh+AlBh+AhBl) => ~16-bit mantissa.
// r12: XW fp16 (gather footprint). Logits from fp32 acc pre-rounding.
// REGISTER-PRESSURE HISTORY: r3 clamp spill / r4 straight-line clustering spill /
// r5 sched_barrier useless / r6 dynamic loop = only reliable scope bound.
template <int K>
__device__ __forceinline__ void mfma_body(int mtile, const float* __restrict__ X,
                                          const unsigned short* __restrict__ Bhi,
                                          const unsigned short* __restrict__ Blo,
                                          const float* __restrict__ a_s, const float* __restrict__ a_d,
                                          __half* __restrict__ XW, float* __restrict__ Ssrc,
                                          float* __restrict__ Sdst, int N) {
    constexpr int NKC = K / 32;
    int t = threadIdx.x, lane = t & 63;
    if (mtile * 16 >= N) return;
    int m0 = mtile * 16;
    int qd = lane >> 4, col = lane & 15;

    int rA = m0 + col;
    rA = rA < N ? rA : N - 1;
    const float* xrow = X + (size_t)rA * K + qd * 8;

    const short8* bh = (const short8*)Bhi;
    const short8* bl = (const short8*)Blo;

    f32x4 acc[4];
    #pragma unroll
    for (int ct = 0; ct < 4; ct++) acc[ct] = (f32x4){0.f, 0.f, 0.f, 0.f};

    #pragma clang loop unroll(disable)
    for (int kc = 0; kc < NKC; kc++) {
        const float* xp = xrow + kc * 32;
        float4 xa = *(const float4*)xp;
        float4 xb = *(const float4*)(xp + 4);
        float xv[8] = {xa.x, xa.y, xa.z, xa.w, xb.x, xb.y, xb.z, xb.w};
        short8 ah, al;
        #pragma unroll
        for (int j = 0; j < 8; j++) {
            unsigned short h = f2bf(xv[j]);
            ah[j] = (short)h;
            al[j] = (short)f2bf(xv[j] - bf2f(h));
        }
        #pragma unroll
        for (int ct = 0; ct < 4; ct++) {
            short8 wh = bh[(ct * NKC + kc) * 64 + lane];
            short8 wl = bl[(ct * NKC + kc) * 64 + lane];
            acc[ct] = __builtin_amdgcn_mfma_f32_16x16x32_bf16(ah, wh, acc[ct], 0, 0, 0);
            acc[ct] = __builtin_amdgcn_mfma_f32_16x16x32_bf16(al, wh, acc[ct], 0, 0, 0);
            acc[ct] = __builtin_amdgcn_mfma_f32_16x16x32_bf16(ah, wl, acc[ct], 0, 0, 0);
        }
    }

    float asx[4], adx[4];
    #pragma unroll
    for (int ct = 0; ct < 4; ct++) {
        asx[ct] = a_s[ct * 16 + col];
        adx[ct] = a_d[ct * 16 + col];
    }
    #pragma unroll
    for (int r = 0; r < 4; r++) {
        int row = m0 + qd * 4 + r;
        if (row < N) {
            float vs = 0.f, vd = 0.f;
            #pragma unroll
            for (int ct = 0; ct < 4; ct++) {
                float v = acc[ct][r];
                XW[(size_t)row * 64 + ct * 16 + col] = __float2half(v);
                vs += v * asx[ct];
                vd += v * adx[ct];
            }
            #pragma unroll
            for (int d = 1; d < 16; d <<= 1) {
                vs += __shfl_xor(vs, d);
                vd += __shfl_xor(vd, d);
            }
            if (col == 0) { Ssrc[row] = vs; Sdst[row] = vd; }
        }
    }
}

// ---------------- r14 heterogeneous fusions ----------------
// hist and scatter are latency-bound (VALUBusy <1%, r13 counters); mfma256 is
// compute-dense and independent of the CSR chain. Single-stream capture forbids
// multi-stream overlap, so overlap INSIDE a launch: first blocks run the CSR
// pass, remaining blocks run half the GEMM tiles. Fused dur ~ latency partner.
__global__ __launch_bounds__(256) void k_histmm(const int* __restrict__ dst, int* __restrict__ deg, int E,
                                                int histBlocks,
                                                const float* __restrict__ X,
                                                const unsigned short* __restrict__ Bhi,
                                                const unsigned short* __restrict__ Blo,
                                                const float* __restrict__ a_s, const float* __restrict__ a_d,
                                                __half* __restrict__ XW, float* __restrict__ Ssrc,
                                                float* __restrict__ Sdst, int N, int tileLim) {
    if ((int)blockIdx.x < histBlocks) {
        int i = blockIdx.x * 256 + threadIdx.x;
        if (i < E) atomicAdd(&deg[dst[i]], 1);
        return;
    }
    int mtile = ((int)blockIdx.x - histBlocks) * 4 + ((int)threadIdx.x >> 6);
    if (mtile >= tileLim) return;
    mfma_body<256>(mtile, X, Bhi, Blo, a_s, a_d, XW, Ssrc, Sdst, N);
}

__global__ __launch_bounds__(256) void k_scatmm(const int* __restrict__ src, const int* __restrict__ dst,
                                                const int* __restrict__ off, const int* __restrict__ bs,
                                                int* __restrict__ cur, int* __restrict__ csr, int E,
                                                int scatBlocks,
                                                const float* __restrict__ X,
                                                const unsigned short* __restrict__ Bhi,
                                                const unsigned short* __restrict__ Blo,
                                                const float* __restrict__ a_s, const float* __restrict__ a_d,
                                                __half* __restrict__ XW, float* __restrict__ Ssrc,
                                                float* __restrict__ Sdst, int N, int tileBase) {
    if ((int)blockIdx.x < scatBlocks) {
        int i = blockIdx.x * 256 + threadIdx.x;
        if (i < E) {
            int d = dst[i];
            int pos = off[d] + bs[d >> 10] + atomicAdd(&cur[d], 1);
            csr[pos] = src[i];
        }
        return;
    }
    int mtile = tileBase + ((int)blockIdx.x - scatBlocks) * 4 + ((int)threadIdx.x >> 6);
    mfma_body<256>(mtile, X, Bhi, Blo, a_s, a_d, XW, Ssrc, Sdst, N);
}

// standalone layer-2 GEMM
__global__ __launch_bounds__(256) void k_mfma64(const float* __restrict__ X,
                                                const unsigned short* __restrict__ Bhi,
                                                const unsigned short* __restrict__ Blo,
                                                const float* __restrict__ a_s, const float* __restrict__ a_d,
                                                __half* __restrict__ XW, float* __restrict__ Ssrc,
                                                float* __restrict__ Sdst, int N) {
    int mtile = blockIdx.x * 4 + ((int)threadIdx.x >> 6);
    mfma_body<64>(mtile, X, Bhi, Blo, a_s, a_d, XW, Ssrc, Sdst, N);
}

// ---------------- attention + aggregate: one wave per dst node (r13 form) ----------------
__global__ __launch_bounds__(256) void k_attn(const __half* __restrict__ XW, const float* __restrict__ Ssrc,
                                              const float* __restrict__ Sdst, const int* __restrict__ csr,
                                              const int* __restrict__ off, const int* __restrict__ bsums,
                                              const int* __restrict__ deg,
                                              const float* __restrict__ bias, float* __restrict__ H,
                                              int N, int do_relu) {
    int t = threadIdx.x, lane = t & 63, wid = t >> 6;
    int n = blockIdx.x * 4 + wid;
    if (n >= N) return;
    int g = lane >> 3, c = lane & 7;
    float sd = Sdst[n];
    int st = off[n] + bsums[n >> 10];
    int d = deg[n];

    float eself = lrelu(Ssrc[n] + sd);
    float m = eself;
    int myS = 0;
    float myE = -1e30f;
    if (lane < d) {
        myS = csr[st + lane];
        myE = lrelu(Ssrc[myS] + sd);
        m = fmaxf(m, myE);
    }
    for (int i = 64 + lane; i < d; i += 64) {
        m = fmaxf(m, lrelu(Ssrc[csr[st + i]] + sd));
    }
    #pragma unroll
    for (int dd = 32; dd > 0; dd >>= 1) m = fmaxf(m, __shfl_xor(m, dd));

    float myW = (lane < d) ? __expf(myE - m) : 0.f;
    float wself = __expf(eself - m);
    float denom = myW;
    #pragma unroll
    for (int dd = 32; dd > 0; dd >>= 1) denom += __shfl_xor(denom, dd);
    denom += wself;  // wave-uniform

    float a8[8];
    #pragma unroll
    for (int j = 0; j < 8; j++) a8[j] = 0.f;

    auto gat = [&](int row, float w) {
        float4 raw = *(const float4*)(XW + (size_t)row * 64 + c * 8);
        const __half2* hp = (const __half2*)&raw;
        #pragma unroll
        for (int j = 0; j < 4; j++) {
            float2 f = __half22float2(hp[j]);
            a8[2 * j] += w * f.x;
            a8[2 * j + 1] += w * f.y;
        }
    };

    gat(n, (g == 0) ? wself : 0.f);
    int dcap = d < 64 ? d : 64;
    for (int i = 0; i < dcap; i += 8) {
        int idx = i + g;
        int si = __shfl(myS, idx);
        float wi = __shfl(myW, idx);
        if (idx >= dcap) wi = 0.f;
        gat(si, wi);
    }
    for (int i = 64; i < d; i++) {             // rare tail
        int s = csr[st + i];
        float e = lrelu(Ssrc[s] + sd);
        float w = __expf(e - m);
        denom += w;
        gat(s, (g == 0) ? w : 0.f);
    }

    #pragma unroll
    for (int mask = 8; mask <= 32; mask <<= 1) {
        #pragma unroll
        for (int j = 0; j < 8; j++) a8[j] += __shfl_xor(a8[j], mask);
    }

    if (g == 0) {
        float inv = 1.f / denom;
        float o[8];
        #pragma unroll
        for (int j = 0; j < 8; j++) {
            o[j] = a8[j] * inv + bias[c * 8 + j];
            if (do_relu) o[j] = fmaxf(o[j], 0.f);
        }
        float4* hp = (float4*)&H[(size_t)n * 64 + c * 8];
        hp[0] = make_float4(o[0], o[1], o[2], o[3]);
        hp[1] = make_float4(o[4], o[5], o[6], o[7]);
    }
}

// ---------------- head ----------------
__global__ __launch_bounds__(256) void k_head(const float* __restrict__ H, const int* __restrict__ ui,
                                              const int* __restrict__ mi, const float* __restrict__ fcW,
                                              const float* __restrict__ fcb, float* __restrict__ out, int B) {
    int t = threadIdx.x, lane = t & 63, wid = t >> 6;
    int i = blockIdx.x * 4 + wid;
    if (i >= B) return;
    int u = ui[i], m = mi[i];
    float v = H[(size_t)u * 64 + lane] * fcW[lane] + H[(size_t)m * 64 + lane] * fcW[64 + lane];
    #pragma unroll
    for (int dd = 32; dd > 0; dd >>= 1) v += __shfl_xor(v, dd);
    if (lane == 0) out[i] = v + fcb[0];
}

extern "C" void kernel_launch(void* const* d_in, const int* in_sizes, int n_in,
                              void* d_out, int out_size, void* d_ws, size_t ws_size,
                              hipStream_t stream) {
    const float* x   = (const float*)d_in[0];
    const int*   ei  = (const int*)d_in[1];
    const int*   ui  = (const int*)d_in[2];
    const int*   mi  = (const int*)d_in[3];
    const float* W1  = (const float*)d_in[4];
    const float* as1 = (const float*)d_in[5];
    const float* ad1 = (const float*)d_in[6];
    const float* b1  = (const float*)d_in[7];
    const float* W2  = (const float*)d_in[8];
    const float* as2 = (const float*)d_in[9];
    const float* ad2 = (const float*)d_in[10];
    const float* b2  = (const float*)d_in[11];
    const float* fcW = (const float*)d_in[12];
    const float* fcb = (const float*)d_in[13];
    float* out = (float*)d_out;

    const int Hdim = in_sizes[5];            // 64
    const int FIN  = in_sizes[4] / Hdim;     // 256
    const int N    = in_sizes[0] / FIN;      // 100000
    const int E    = in_sizes[1] / 2;        // 1000000
    const int B    = in_sizes[2];            // 16384

    char* w = (char*)d_ws;
    auto alloc = [&](size_t bytes) -> void* {
        void* p = (void*)w;
        w += (bytes + 255) & ~(size_t)255;
        return p;
    };
    __half* xw  = (__half*)alloc((size_t)N * 64 * 2);
    float* hbuf = (float*)alloc((size_t)N * 64 * 4);
    float* ssrc = (float*)alloc((size_t)N * 4);
    float* sdst = (float*)alloc((size_t)N * 4);
    int* degcur = (int*)alloc((size_t)2 * N * 4);
    int* deg = degcur;
    int* cur = degcur + N;
    int* offv  = (int*)alloc((size_t)N * 4);
    int* bsums = (int*)alloc((size_t)1024 * 4);
    int* csr   = (int*)alloc((size_t)E * 4);
    unsigned short* b1hi = (unsigned short*)alloc((size_t)2048 * 8 * 2);
    unsigned short* b1lo = (unsigned short*)alloc((size_t)2048 * 8 * 2);
    unsigned short* b2hi = (unsigned short*)alloc((size_t)512 * 8 * 2);
    unsigned short* b2lo = (unsigned short*)alloc((size_t)512 * 8 * 2);

    const int* esrc = ei;
    const int* edst = ei + E;

    // --- prep: zero counters + pack both W (packs must precede any mfma) ---
    int prepWork = 2 * N + 2048 + 512;
    k_prep<<<(prepWork + 255) / 256, 256, 0, stream>>>(degcur, 2 * N, W1, b1hi, b1lo, W2, b2hi, b2lo);

    const int tilesTotal = (N + 15) / 16;          // 6250
    const int tilesA = tilesTotal / 2;             // first half with hist
    const int blocksA = (tilesA + 3) / 4;
    const int blocksB = (tilesTotal - tilesA + 3) / 4;
    const int csrBlocks = (E + 255) / 256;

    // --- hist ∥ mfma256 (first half of tiles) ---
    k_histmm<<<csrBlocks + blocksA, 256, 0, stream>>>(edst, deg, E, csrBlocks,
                                                      x, b1hi, b1lo, as1, ad1, xw, ssrc, sdst, N, tilesA);
    int nb = (N + 1023) / 1024;
    k_scan1<<<nb, 1024, 0, stream>>>(deg, offv, bsums, N);
    k_scan2<<<1, 1024, 0, stream>>>(bsums, nb);
    // --- scatter ∥ mfma256 (second half of tiles) ---
    k_scatmm<<<csrBlocks + blocksB, 256, 0, stream>>>(esrc, edst, offv, bsums, cur, csr, E, csrBlocks,
                                                      x, b1hi, b1lo, as1, ad1, xw, ssrc, sdst, N, tilesA);

    // --- layer 1 attention ---
    k_attn<<<(N + 3) / 4, 256, 0, stream>>>(xw, ssrc, sdst, csr, offv, bsums, deg, b1, hbuf, N, 1);

    // --- layer 2 ---
    k_mfma64<<<(tilesTotal + 3) / 4, 256, 0, stream>>>(hbuf, b2hi, b2lo, as2, ad2, xw, ssrc, sdst, N);
    k_attn<<<(N + 3) / 4, 256, 0, stream>>>(xw, ssrc, sdst, csr, offv, bsums, deg, b2, hbuf, N, 0);

    // --- head ---
    k_head<<<(B + 3) / 4, 256, 0, stream>>>(hbuf, ui, mi, fcW, fcb, out, B);
}